// Round 6
// baseline (1598.530 us; speedup 1.0000x reference)
//
#include <hip/hip_runtime.h>
#include <hip/hip_bf16.h>
#include <math.h>

#define IN_DIM 172
#define HID 128
#define TDIM 100
#define KPAD 192

typedef __attribute__((ext_vector_type(8))) short bf16x8;
typedef __attribute__((ext_vector_type(4))) float f32x4;

static __device__ __forceinline__ ushort f2b(float x) {
  unsigned u = __float_as_uint(x);
  u += 0x7FFFu + ((u >> 16) & 1u);
  return (ushort)(u >> 16);
}
static __device__ __forceinline__ float blo(unsigned w) { return __uint_as_float(w << 16); }
static __device__ __forceinline__ float bhi(unsigned w) { return __uint_as_float(w & 0xffff0000u); }

// ---- one-shot weight prep: wpt | wallT(2 layers)+ball | wet(2) | w1t ----
__global__ void k_prep(const float* __restrict__ Wp,
                       const float* __restrict__ Wq, const float* __restrict__ Wk,
                       const float* __restrict__ Wv, const float* __restrict__ Ws,
                       const float* __restrict__ bq, const float* __restrict__ bk,
                       const float* __restrict__ bv, const float* __restrict__ bs,
                       const float* __restrict__ We, const float* __restrict__ W1,
                       ushort* __restrict__ wpt,
                       ushort* __restrict__ wallT0, ushort* __restrict__ wallT1,
                       float* __restrict__ ball0, float* __restrict__ ball1,
                       ushort* __restrict__ wet0, ushort* __restrict__ wet1,
                       ushort* __restrict__ w1t) {
  int i = blockIdx.x * 256 + threadIdx.x;
  if (i < 128 * KPAD) {
    int c = i / KPAD, k = i - c * KPAD;
    wpt[i] = (k < IN_DIM) ? f2b(Wp[k * HID + c]) : (ushort)0;
    return;
  }
  i -= 128 * KPAD;
  if (i < 2 * 512 * 128) {
    int layer = i >> 16;
    int j = i & 65535;
    int col = j >> 7, k = j & 127;
    int m = col >> 7, c = col & 127;
    const float* W = (m == 0) ? Wq : (m == 1) ? Wk : (m == 2) ? Wv : Ws;
    W += (size_t)layer * HID * HID;
    (layer ? wallT1 : wallT0)[j] = f2b(W[k * HID + c]);
    if (k == 0) {
      const float* bb = (m == 0) ? bq : (m == 1) ? bk : (m == 2) ? bv : bs;
      (layer ? ball1 : ball0)[col] = bb[layer * HID + c];
    }
    return;
  }
  i -= 2 * 512 * 128;
  if (i < 2 * 128 * 128) {
    int layer = i >> 14;
    int j = i & 16383;
    int c = j >> 7, t = j & 127;
    (layer ? wet1 : wet0)[j] =
        (t < TDIM) ? f2b(We[((size_t)layer * TDIM + t) * HID + c]) : (ushort)0;
    return;
  }
  i -= 2 * 128 * 128;
  if (i < 128 * 128) {
    int c = i >> 7, k = i & 127;
    w1t[i] = f2b(W1[k * HID + c]);
  }
}

// h = relu(x_all[ids] @ Wp + bp) -> bf16, via MFMA, 64 rows/block
__global__ __launch_bounds__(256) void k_in_mfma(
    const float* __restrict__ x_all, const int* __restrict__ ids,
    const ushort* __restrict__ wpt, const float* __restrict__ bp,
    ushort* __restrict__ h, int n) {
  __shared__ __align__(16) ushort xs[64][200];
  int tid = threadIdx.x;
  long r0 = (long)blockIdx.x * 64;
  for (int i = tid; i < 64 * 28; i += 256) {
    int r = i / 28, c = IN_DIM + (i - r * 28);
    xs[r][c] = 0;
  }
  for (int i = tid; i < 64 * 43; i += 256) {
    int r = i / 43, seg = i - r * 43;
    long row = r0 + r;
    float4 v = make_float4(0.f, 0.f, 0.f, 0.f);
    if (row < n) v = *(const float4*)(x_all + (size_t)ids[row] * IN_DIM + seg * 4);
    ushort4 u;
    u.x = f2b(v.x); u.y = f2b(v.y); u.z = f2b(v.z); u.w = f2b(v.w);
    *(ushort4*)&xs[r][seg * 4] = u;
  }
  __syncthreads();
  int wv = tid >> 6, l = tid & 63;
  int arow = wv * 16 + (l & 15);
  int kb0 = (l >> 4) * 8;
  bf16x8 a[6];
  #pragma unroll
  for (int kk = 0; kk < 6; ++kk) a[kk] = *(const bf16x8*)&xs[arow][kk * 32 + kb0];
  #pragma unroll
  for (int nt = 0; nt < 8; ++nt) {
    int col = nt * 16 + (l & 15);
    const ushort* wcol = wpt + (size_t)col * KPAD + kb0;
    f32x4 acc = {0.f, 0.f, 0.f, 0.f};
    #pragma unroll
    for (int kk = 0; kk < 6; ++kk) {
      bf16x8 bfr = *(const bf16x8*)(wcol + kk * 32);
      acc = __builtin_amdgcn_mfma_f32_16x16x32_bf16(a[kk], bfr, acc, 0, 0, 0);
    }
    float bias = bp[col];
    #pragma unroll
    for (int j = 0; j < 4; ++j) {
      long row = r0 + wv * 16 + (l >> 4) * 4 + j;
      if (row < n) {
        float y = acc[j] + bias;
        h[row * HID + col] = f2b(y > 0.f ? y : 0.f);
      }
    }
  }
}

// fused q/k/v/skip, optionally applying bn(relu(.)) to f32 input on load
template <bool BN_IN>
__global__ __launch_bounds__(512) void k_qkvs(
    const ushort* __restrict__ hbf, const float* __restrict__ xf,
    const float* __restrict__ sums, const float* __restrict__ bng,
    const float* __restrict__ bnb, float inv_n,
    const ushort* __restrict__ wallT, const float* __restrict__ ball,
    ushort* __restrict__ qb, ushort* __restrict__ kbuf, ushort* __restrict__ vb,
    float* __restrict__ ob, int n) {
  __shared__ __align__(16) ushort hs[128][136];
  __shared__ __align__(16) ushort ws[64][136];
  __shared__ float As[128], Bs[128];
  int tid = threadIdx.x;
  if (BN_IN) {
    if (tid < 128) {
      float mean = sums[tid] * inv_n;
      float var = sums[128 + tid] * inv_n - mean * mean;
      float A = bng[tid] * rsqrtf(var + 1e-5f);
      As[tid] = A;
      Bs[tid] = bnb[tid] - mean * A;
    }
    __syncthreads();
  }
  long r0 = (long)blockIdx.x * 128;
  for (int i = tid; i < 128 * 16; i += 512) {
    int r = i >> 4, cseg = i & 15;
    long row = r0 + r;
    int c0 = cseg * 8;
    if (BN_IN) {
      ushort4 ua = {0, 0, 0, 0}, ub = {0, 0, 0, 0};
      if (row < n) {
        const float* xr = xf + row * HID + c0;
        float4 xa = *(const float4*)xr;
        float4 xb = *(const float4*)(xr + 4);
        ua.x = f2b(As[c0 + 0] * fmaxf(xa.x, 0.f) + Bs[c0 + 0]);
        ua.y = f2b(As[c0 + 1] * fmaxf(xa.y, 0.f) + Bs[c0 + 1]);
        ua.z = f2b(As[c0 + 2] * fmaxf(xa.z, 0.f) + Bs[c0 + 2]);
        ua.w = f2b(As[c0 + 3] * fmaxf(xa.w, 0.f) + Bs[c0 + 3]);
        ub.x = f2b(As[c0 + 4] * fmaxf(xb.x, 0.f) + Bs[c0 + 4]);
        ub.y = f2b(As[c0 + 5] * fmaxf(xb.y, 0.f) + Bs[c0 + 5]);
        ub.z = f2b(As[c0 + 6] * fmaxf(xb.z, 0.f) + Bs[c0 + 6]);
        ub.w = f2b(As[c0 + 7] * fmaxf(xb.w, 0.f) + Bs[c0 + 7]);
      }
      *(ushort4*)&hs[r][c0] = ua;
      *(ushort4*)&hs[r][c0 + 4] = ub;
    } else {
      bf16x8 zv = {0, 0, 0, 0, 0, 0, 0, 0};
      bf16x8 v = (row < n) ? *(const bf16x8*)&hbf[row * HID + c0] : zv;
      *(bf16x8*)&hs[r][c0] = v;
    }
  }
  __syncthreads();
  int wv = tid >> 6, l = tid & 63;
  int arow = wv * 16 + (l & 15);
  int kb0 = (l >> 4) * 8;
  bf16x8 a[4];
  #pragma unroll
  for (int kk = 0; kk < 4; ++kk) a[kk] = *(const bf16x8*)&hs[arow][kk * 32 + kb0];

  for (int g = 0; g < 8; ++g) {
    __syncthreads();
    for (int i = tid; i < 64 * 16; i += 512) {
      int c = i >> 4, cseg = i & 15;
      *(bf16x8*)&ws[c][cseg * 8] =
          *(const bf16x8*)&wallT[(size_t)(g * 64 + c) * 128 + cseg * 8];
    }
    __syncthreads();
    #pragma unroll
    for (int nt = 0; nt < 4; ++nt) {
      int colc = nt * 16 + (l & 15);
      int gcol = g * 64 + colc;
      f32x4 acc = {0.f, 0.f, 0.f, 0.f};
      #pragma unroll
      for (int kk = 0; kk < 4; ++kk) {
        bf16x8 bfr = *(const bf16x8*)&ws[colc][kk * 32 + kb0];
        acc = __builtin_amdgcn_mfma_f32_16x16x32_bf16(a[kk], bfr, acc, 0, 0, 0);
      }
      float bias = ball[gcol];
      int m = gcol >> 7, c = gcol & 127;
      #pragma unroll
      for (int j = 0; j < 4; ++j) {
        long row = r0 + wv * 16 + (l >> 4) * 4 + j;
        if (row < n) {
          float y = acc[j] + bias;
          if (m == 3) ob[row * HID + c] = y;
          else {
            ushort* db = (m == 0) ? qb : (m == 1) ? kbuf : vb;
            db[row * HID + c] = f2b(y);
          }
        }
      }
    }
  }
}

// head GEMM: y = bn_relu(ob1 rows) @ W1T + b1 -> f32 z1, 64 rows/block
__global__ __launch_bounds__(256) void k_mfma128_bn(
    const float* __restrict__ xf, const float* __restrict__ sums,
    const float* __restrict__ bng, const float* __restrict__ bnb, float inv_n,
    const ushort* __restrict__ WT, const float* __restrict__ bias,
    float* __restrict__ Y, int n) {
  __shared__ __align__(16) ushort hs[64][136];
  __shared__ float As[128], Bs[128];
  int tid = threadIdx.x;
  if (tid < 128) {
    float mean = sums[tid] * inv_n;
    float var = sums[128 + tid] * inv_n - mean * mean;
    float A = bng[tid] * rsqrtf(var + 1e-5f);
    As[tid] = A;
    Bs[tid] = bnb[tid] - mean * A;
  }
  __syncthreads();
  long r0 = (long)blockIdx.x * 64;
  for (int i = tid; i < 64 * 16; i += 256) {
    int r = i >> 4, cseg = i & 15;
    long row = r0 + r;
    int c0 = cseg * 8;
    ushort4 ua = {0, 0, 0, 0}, ub = {0, 0, 0, 0};
    if (row < n) {
      const float* xr = xf + row * HID + c0;
      float4 xa = *(const float4*)xr;
      float4 xb = *(const float4*)(xr + 4);
      ua.x = f2b(As[c0 + 0] * fmaxf(xa.x, 0.f) + Bs[c0 + 0]);
      ua.y = f2b(As[c0 + 1] * fmaxf(xa.y, 0.f) + Bs[c0 + 1]);
      ua.z = f2b(As[c0 + 2] * fmaxf(xa.z, 0.f) + Bs[c0 + 2]);
      ua.w = f2b(As[c0 + 3] * fmaxf(xa.w, 0.f) + Bs[c0 + 3]);
      ub.x = f2b(As[c0 + 4] * fmaxf(xb.x, 0.f) + Bs[c0 + 4]);
      ub.y = f2b(As[c0 + 5] * fmaxf(xb.y, 0.f) + Bs[c0 + 5]);
      ub.z = f2b(As[c0 + 6] * fmaxf(xb.z, 0.f) + Bs[c0 + 6]);
      ub.w = f2b(As[c0 + 7] * fmaxf(xb.w, 0.f) + Bs[c0 + 7]);
    }
    *(ushort4*)&hs[r][c0] = ua;
    *(ushort4*)&hs[r][c0 + 4] = ub;
  }
  __syncthreads();
  int wv = tid >> 6, l = tid & 63;
  int arow = wv * 16 + (l & 15);
  int kb0 = (l >> 4) * 8;
  bf16x8 a[4];
  #pragma unroll
  for (int kk = 0; kk < 4; ++kk) a[kk] = *(const bf16x8*)&hs[arow][kk * 32 + kb0];
  #pragma unroll
  for (int nt = 0; nt < 8; ++nt) {
    int col = nt * 16 + (l & 15);
    const ushort* wcol = WT + (size_t)col * 128 + kb0;
    f32x4 acc = {0.f, 0.f, 0.f, 0.f};
    #pragma unroll
    for (int kk = 0; kk < 4; ++kk) {
      bf16x8 bfr = *(const bf16x8*)(wcol + kk * 32);
      acc = __builtin_amdgcn_mfma_f32_16x16x32_bf16(a[kk], bfr, acc, 0, 0, 0);
    }
    float bs = bias[col];
    #pragma unroll
    for (int j = 0; j < 4; ++j) {
      long row = r0 + wv * 16 + (l >> 4) * 4 + j;
      if (row < n) Y[row * HID + col] = acc[j] + bs;
    }
  }
}

// ---- counting sort by dst ----
__global__ void k_hist(const int* __restrict__ dst, int* __restrict__ counts, int nE) {
  int e = blockIdx.x * 256 + threadIdx.x;
  if (e < nE) atomicAdd(&counts[dst[e]], 1);
}

// single-block exclusive scan over counts -> offs
__global__ __launch_bounds__(1024) void k_scan(const int* __restrict__ counts,
                                               int* __restrict__ offs, int n, int nE) {
  __shared__ int ls[1024];
  int t = threadIdx.x;
  int chunk = (n + 1023) >> 10;
  int b0 = t * chunk;
  int sum = 0;
  for (int j = 0; j < chunk; ++j) {
    int idx = b0 + j;
    if (idx < n) sum += counts[idx];
  }
  ls[t] = sum;
  __syncthreads();
  for (int off = 1; off < 1024; off <<= 1) {
    int x = (t >= off) ? ls[t - off] : 0;
    __syncthreads();
    ls[t] += x;
    __syncthreads();
  }
  int run = (t == 0) ? 0 : ls[t - 1];
  for (int j = 0; j < chunk; ++j) {
    int idx = b0 + j;
    if (idx < n) {
      offs[idx] = run;
      run += counts[idx];
    }
  }
  if (t == 0) offs[n] = nE;
}

__global__ void k_scatter(const int* __restrict__ src, const int* __restrict__ dst,
                          const float* __restrict__ dts, const int* __restrict__ offs,
                          int* __restrict__ cursor, uint2* __restrict__ edata, int nE) {
  int e = blockIdx.x * 256 + threadIdx.x;
  if (e >= nE) return;
  int d = dst[e];
  int pos = offs[d] + atomicAdd(&cursor[d], 1);
  edata[pos] = make_uint2((unsigned)src[e], __float_as_uint(dts[e]));
}

// e[E][128] = cos(dt*f+p) @ We via MFMA, bf16 out (sorted order)
__global__ __launch_bounds__(256) void k_te_mfma(
    const uint2* __restrict__ edata, const float* __restrict__ freq,
    const float* __restrict__ phase, const ushort* __restrict__ wet,
    ushort* __restrict__ eb, int nE) {
  __shared__ __align__(16) ushort te[64][136];
  __shared__ float dt_s[64];
  __shared__ float fr_s[128], ph_s[128];
  int tid = threadIdx.x;
  if (tid < 128) {
    fr_s[tid] = (tid < TDIM) ? freq[tid] : 0.f;
    ph_s[tid] = (tid < TDIM) ? phase[tid] : 0.f;
  }
  long e0 = (long)blockIdx.x << 6;
  if (tid < 64) dt_s[tid] = (e0 + tid < nE) ? __uint_as_float(edata[e0 + tid].y) : 0.f;
  __syncthreads();
  for (int i = tid; i < 64 * 128; i += 256) {
    int el = i >> 7, t = i & 127;
    float val = (t < TDIM) ? __cosf(dt_s[el] * fr_s[t] + ph_s[t]) : 0.f;
    te[el][t] = f2b(val);
  }
  __syncthreads();
  int wv = tid >> 6, l = tid & 63;
  int arow = wv * 16 + (l & 15);
  int kb0 = (l >> 4) * 8;
  bf16x8 a[4];
  #pragma unroll
  for (int kk = 0; kk < 4; ++kk) a[kk] = *(const bf16x8*)&te[arow][kk * 32 + kb0];
  #pragma unroll
  for (int nt = 0; nt < 8; ++nt) {
    int col = nt * 16 + (l & 15);
    const ushort* wcol = wet + (size_t)col * 128 + kb0;
    f32x4 acc = {0.f, 0.f, 0.f, 0.f};
    #pragma unroll
    for (int kk = 0; kk < 4; ++kk) {
      bf16x8 bfr = *(const bf16x8*)(wcol + kk * 32);
      acc = __builtin_amdgcn_mfma_f32_16x16x32_bf16(a[kk], bfr, acc, 0, 0, 0);
    }
    #pragma unroll
    for (int j = 0; j < 4; ++j) {
      long row = e0 + wv * 16 + (l >> 4) * 4 + j;
      if (row < nE) eb[row * 128 + col] = f2b(acc[j]);
    }
  }
}

// fused attention: one wave per dst, 4 edges/iter (16-lane subgroups), online softmax
__global__ void k_attn(const int* __restrict__ offs, const uint2* __restrict__ edata,
                       const ushort* __restrict__ eb, const ushort* __restrict__ qb,
                       const ushort* __restrict__ kb, const ushort* __restrict__ vb,
                       float* __restrict__ ob, int n) {
  int d = (blockIdx.x * 256 + threadIdx.x) >> 6;
  if (d >= n) return;
  int lane = threadIdx.x & 63;
  int sub = lane >> 4;
  int cl = lane & 15;
  int c0 = cl * 8;
  int beg = offs[d], end = offs[d + 1];
  if (beg == end) return;
  uint4 qw = *(const uint4*)(qb + (size_t)d * HID + c0);
  float q0 = blo(qw.x), q1 = bhi(qw.x), q2 = blo(qw.y), q3 = bhi(qw.y);
  float q4 = blo(qw.z), q5 = bhi(qw.z), q6 = blo(qw.w), q7 = bhi(qw.w);
  float m = -INFINITY, s = 0.f;
  float a0 = 0.f, a1 = 0.f, a2 = 0.f, a3 = 0.f, a4 = 0.f, a5 = 0.f, a6 = 0.f, a7 = 0.f;
  for (int base = beg; base < end; base += 4) {
    int pos = base + sub;
    bool valid = pos < end;
    int pp = valid ? pos : beg;
    int sv = (int)edata[pp].x;
    uint4 kw = *(const uint4*)(kb + (size_t)sv * HID + c0);
    uint4 vw = *(const uint4*)(vb + (size_t)sv * HID + c0);
    uint4 ew = *(const uint4*)(eb + (size_t)pp * HID + c0);
    float e0 = blo(ew.x), e1 = bhi(ew.x), e2 = blo(ew.y), e3 = bhi(ew.y);
    float e4 = blo(ew.z), e5 = bhi(ew.z), e6 = blo(ew.w), e7 = bhi(ew.w);
    float p = q0 * (blo(kw.x) + e0) + q1 * (bhi(kw.x) + e1) +
              q2 * (blo(kw.y) + e2) + q3 * (bhi(kw.y) + e3) +
              q4 * (blo(kw.z) + e4) + q5 * (bhi(kw.z) + e5) +
              q6 * (blo(kw.w) + e6) + q7 * (bhi(kw.w) + e7);
    p += __shfl_xor(p, 1);
    p += __shfl_xor(p, 2);  // per-head dot (4 lanes = 32 cols)
    float av = valid ? p * 0.17677669529663687f : -INFINITY;
    float nm = fmaxf(m, av);
    float sc = (m > -INFINITY) ? __expf(m - nm) : 0.f;
    float pe = valid ? __expf(av - nm) : 0.f;
    m = nm;
    s = s * sc + pe;
    a0 = a0 * sc + pe * (blo(vw.x) + e0);
    a1 = a1 * sc + pe * (bhi(vw.x) + e1);
    a2 = a2 * sc + pe * (blo(vw.y) + e2);
    a3 = a3 * sc + pe * (bhi(vw.y) + e3);
    a4 = a4 * sc + pe * (blo(vw.z) + e4);
    a5 = a5 * sc + pe * (bhi(vw.z) + e5);
    a6 = a6 * sc + pe * (blo(vw.w) + e6);
    a7 = a7 * sc + pe * (bhi(vw.w) + e7);
  }
  // merge the 4 subgroups
  #pragma unroll
  for (int off = 16; off <= 32; off <<= 1) {
    float mo = __shfl_xor(m, off);
    float so = __shfl_xor(s, off);
    float t0 = __shfl_xor(a0, off), t1 = __shfl_xor(a1, off);
    float t2 = __shfl_xor(a2, off), t3 = __shfl_xor(a3, off);
    float t4 = __shfl_xor(a4, off), t5 = __shfl_xor(a5, off);
    float t6 = __shfl_xor(a6, off), t7 = __shfl_xor(a7, off);
    float nm = fmaxf(m, mo);
    float s1 = (m > -INFINITY) ? __expf(m - nm) : 0.f;
    float s2 = (mo > -INFINITY) ? __expf(mo - nm) : 0.f;
    s = s * s1 + so * s2;
    a0 = a0 * s1 + t0 * s2; a1 = a1 * s1 + t1 * s2;
    a2 = a2 * s1 + t2 * s2; a3 = a3 * s1 + t3 * s2;
    a4 = a4 * s1 + t4 * s2; a5 = a5 * s1 + t5 * s2;
    a6 = a6 * s1 + t6 * s2; a7 = a7 * s1 + t7 * s2;
    m = nm;
  }
  if (sub == 0) {
    float inv = 1.f / (s + 1e-16f);
    float4* o = (float4*)(ob + (size_t)d * HID + c0);
    float4 x0 = o[0], x1 = o[1];
    x0.x += a0 * inv; x0.y += a1 * inv; x0.z += a2 * inv; x0.w += a3 * inv;
    x1.x += a4 * inv; x1.y += a5 * inv; x1.z += a6 * inv; x1.w += a7 * inv;
    o[0] = x0; o[1] = x1;
  }
}

template <bool PRE_RELU>
__global__ void k_bn_reduce(const float* __restrict__ X, int n, int C, int shift,
                            float* __restrict__ sums) {
  int col = threadIdx.x & (C - 1);
  int rloc = threadIdx.x >> shift;
  int rpt = 256 >> shift;
  float s = 0.f, s2 = 0.f;
  for (long r = (long)blockIdx.x * rpt + rloc; r < n; r += (long)gridDim.x * rpt) {
    float v = X[r * C + col];
    if (PRE_RELU) v = v > 0.f ? v : 0.f;
    s += v; s2 += v * v;
  }
  __shared__ float ls[256], ls2[256];
  ls[threadIdx.x] = s; ls2[threadIdx.x] = s2;
  __syncthreads();
  if (rloc == 0) {
    for (int j = 1; j < rpt; ++j) { s += ls[j * C + col]; s2 += ls2[j * C + col]; }
    atomicAdd(&sums[col], s);
    atomicAdd(&sums[C + col], s2);
  }
}

// z2 = relu(bn(z1)) @ W2 + b2 (BN fused on load), 16 rows/block
__global__ __launch_bounds__(256) void k_gemm_64(
    const float* __restrict__ X, const float* __restrict__ sums,
    const float* __restrict__ g, const float* __restrict__ be, float inv_n,
    const float* __restrict__ W, const float* __restrict__ b,
    float* __restrict__ Y, int n) {
  __shared__ float xs[16][HID];
  __shared__ float As[128], Bs[128];
  if (threadIdx.x < 128) {
    int c = threadIdx.x;
    float mean = sums[c] * inv_n;
    float var = sums[128 + c] * inv_n - mean * mean;
    float A = g[c] * rsqrtf(var + 1e-5f);
    As[c] = A;
    Bs[c] = be[c] - mean * A;
  }
  __syncthreads();
  int r0 = blockIdx.x * 16;
  for (int idx = threadIdx.x; idx < 16 * HID; idx += 256) {
    int r = idx >> 7, c = idx & 127;
    int row = r0 + r;
    float v = (row < n) ? X[(size_t)row * HID + c] : 0.f;
    v = As[c] * v + Bs[c];
    xs[r][c] = v > 0.f ? v : 0.f;
  }
  __syncthreads();
  int col = threadIdx.x & 63;
  int rg = threadIdx.x >> 6;
  float acc[4] = {0.f, 0.f, 0.f, 0.f};
  #pragma unroll 4
  for (int kk = 0; kk < HID; ++kk) {
    float w = W[kk * 64 + col];
    #pragma unroll
    for (int j = 0; j < 4; ++j) acc[j] += xs[rg + 4 * j][kk] * w;
  }
  float bias = b[col];
  #pragma unroll
  for (int j = 0; j < 4; ++j) {
    int row = r0 + rg + 4 * j;
    if (row < n) Y[(size_t)row * 64 + col] = acc[j] + bias;
  }
}

// out = relu(bn(z2)) . W3 + b3 (BN fused), one wave per row
__global__ __launch_bounds__(256) void k_final(
    const float* __restrict__ z2, const float* __restrict__ sums,
    const float* __restrict__ g2, const float* __restrict__ be2, float inv_n,
    const float* __restrict__ W3, const float* __restrict__ b3,
    float* __restrict__ out, int n) {
  int wave = threadIdx.x >> 6, lane = threadIdx.x & 63;
  int row = blockIdx.x * 4 + wave;
  if (row >= n) return;
  float z = z2[(size_t)row * 64 + lane];
  float mean = sums[lane] * inv_n;
  float var = sums[64 + lane] * inv_n - mean * mean;
  float v = g2[lane] * (z - mean) * rsqrtf(var + 1e-5f) + be2[lane];
  v = v > 0.f ? v : 0.f;
  float pv = v * W3[lane];
  pv += __shfl_xor(pv, 1);
  pv += __shfl_xor(pv, 2);
  pv += __shfl_xor(pv, 4);
  pv += __shfl_xor(pv, 8);
  pv += __shfl_xor(pv, 16);
  pv += __shfl_xor(pv, 32);
  if (lane == 0) out[row] = pv + b3[0];
}

extern "C" void kernel_launch(void* const* d_in, const int* in_sizes, int n_in,
                              void* d_out, int out_size, void* d_ws, size_t ws_size,
                              hipStream_t stream) {
  const float* x_all = (const float*)d_in[0];
  const int* ids = (const int*)d_in[1];
  const int* esrc = (const int*)d_in[2];
  const int* edst = (const int*)d_in[3];
  const float* dts = (const float*)d_in[4];
  const float* freq = (const float*)d_in[6];
  const float* phase = (const float*)d_in[7];
  const float* Wp = (const float*)d_in[8];
  const float* bp = (const float*)d_in[9];
  const float* Wq = (const float*)d_in[10];
  const float* bq = (const float*)d_in[11];
  const float* Wk = (const float*)d_in[12];
  const float* bk = (const float*)d_in[13];
  const float* Wv = (const float*)d_in[14];
  const float* bv = (const float*)d_in[15];
  const float* We = (const float*)d_in[16];
  const float* Wskip = (const float*)d_in[17];
  const float* bskip = (const float*)d_in[18];
  const float* bn_g = (const float*)d_in[19];
  const float* bn_b = (const float*)d_in[20];
  const float* W1 = (const float*)d_in[21];
  const float* b1 = (const float*)d_in[22];
  const float* g1 = (const float*)d_in[23];
  const float* be1 = (const float*)d_in[24];
  const float* W2 = (const float*)d_in[25];
  const float* b2 = (const float*)d_in[26];
  const float* g2 = (const float*)d_in[27];
  const float* be2 = (const float*)d_in[28];
  const float* W3 = (const float*)d_in[29];
  const float* b3 = (const float*)d_in[30];

  size_t n = (size_t)in_sizes[1];
  size_t nE = (size_t)in_sizes[2] / 2;
  int B = out_size;

  char* pc = (char*)d_ws;
  auto alloc = [&](size_t bytes) { char* r = pc; pc += (bytes + 255) & ~(size_t)255; return r; };
  ushort* h    = (ushort*)alloc(n * HID * 2);
  ushort* qb   = (ushort*)alloc(n * HID * 2);
  ushort* kb   = (ushort*)alloc(n * HID * 2);
  ushort* vb   = (ushort*)alloc(n * HID * 2);
  float*  ob0  = (float*)alloc(n * HID * 4);
  float*  ob1  = (float*)alloc(n * HID * 4);
  ushort* eb   = (ushort*)alloc(nE * HID * 2);
  uint2* edata = (uint2*)alloc(nE * 8);
  int* offs    = (int*)alloc((n + 1) * 4);
  // bulk-zeroed region: counts/cursor x2 layers + 4 sums buffers
  size_t zbytes = 4 * n * 4 + 4 * 256 * 4;
  char* zb = alloc(zbytes);
  int* counts0 = (int*)zb;
  int* cursor0 = counts0 + n;
  int* counts1 = cursor0 + n;
  int* cursor1 = counts1 + n;
  float* sumsL0 = (float*)(cursor1 + n);
  float* sumsL1 = sumsL0 + 256;
  float* sumsZ1 = sumsL1 + 256;
  float* sumsZ2 = sumsZ1 + 256;
  ushort* wpt    = (ushort*)alloc(128 * KPAD * 2);
  ushort* wallT0 = (ushort*)alloc(512 * 128 * 2);
  ushort* wallT1 = (ushort*)alloc(512 * 128 * 2);
  float* ball0   = (float*)alloc(512 * 4);
  float* ball1   = (float*)alloc(512 * 4);
  ushort* wet0   = (ushort*)alloc(128 * 128 * 2);
  ushort* wet1   = (ushort*)alloc(128 * 128 * 2);
  ushort* w1t    = (ushort*)alloc(128 * 128 * 2);
  float* z1      = (float*)alloc((size_t)B * HID * 4);
  float* z2      = (float*)alloc((size_t)B * 64 * 4);

  int gn64 = (int)((n + 63) / 64);
  int gn128 = (int)((n + 127) / 128);
  int ge256 = (int)((nE + 255) / 256);
  int eblk = (int)((nE + 63) / 64);
  float inv_nf = 1.f / (float)n;
  float inv_bf = 1.f / (float)B;

  hipMemsetAsync(zb, 0, zbytes, stream);
  k_prep<<<(128 * KPAD + 2 * 512 * 128 + 2 * 128 * 128 + 128 * 128 + 255) / 256, 256, 0, stream>>>(
      Wp, Wq, Wk, Wv, Wskip, bq, bk, bv, bskip, We, W1,
      wpt, wallT0, wallT1, ball0, ball1, wet0, wet1, w1t);
  k_in_mfma<<<gn64, 256, 0, stream>>>(x_all, ids, wpt, bp, h, (int)n);

  for (int i = 0; i < 2; ++i) {
    const int* src_i = esrc + i * nE;
    const int* dst_i = edst + i * nE;
    const float* dts_i = dts + i * nE;
    int* counts = i ? counts1 : counts0;
    int* cursor = i ? cursor1 : cursor0;
    const ushort* wallT = i ? wallT1 : wallT0;
    const float* ball = i ? ball1 : ball0;
    const ushort* wet = i ? wet1 : wet0;
    float* ob = i ? ob1 : ob0;

    if (i == 0)
      k_qkvs<false><<<gn128, 512, 0, stream>>>(h, nullptr, nullptr, nullptr, nullptr, 0.f,
                                               wallT, ball, qb, kb, vb, ob, (int)n);
    else
      k_qkvs<true><<<gn128, 512, 0, stream>>>(nullptr, ob0, sumsL0, bn_g, bn_b, inv_nf,
                                              wallT, ball, qb, kb, vb, ob, (int)n);

    k_hist<<<ge256, 256, 0, stream>>>(dst_i, counts, (int)nE);
    k_scan<<<1, 1024, 0, stream>>>(counts, offs, (int)n, (int)nE);
    k_scatter<<<ge256, 256, 0, stream>>>(src_i, dst_i, dts_i, offs, cursor, edata, (int)nE);
    k_te_mfma<<<eblk, 256, 0, stream>>>(edata, freq, phase, wet, eb, (int)nE);
    k_attn<<<(int)((n + 3) / 4), 256, 0, stream>>>(offs, edata, eb, qb, kb, vb, ob, (int)n);
    k_bn_reduce<true><<<512, 256, 0, stream>>>(ob, (int)n, HID, 7, i ? sumsL1 : sumsL0);
  }

  // MLP head on first B rows (BN of layer-1 fused into the GEMM input)
  k_mfma128_bn<<<(B + 63) / 64, 256, 0, stream>>>(ob1, sumsL1, bn_g + HID, bn_b + HID,
                                                  inv_nf, w1t, b1, z1, B);
  k_bn_reduce<false><<<512, 256, 0, stream>>>(z1, B, HID, 7, sumsZ1);
  k_gemm_64<<<(B + 15) / 16, 256, 0, stream>>>(z1, sumsZ1, g1, be1, inv_bf, W2, b2, z2, B);
  k_bn_reduce<false><<<512, 256, 0, stream>>>(z2, B, 64, 6, sumsZ2);
  k_final<<<(B + 3) / 4, 256, 0, stream>>>(z2, sumsZ2, g2, be2, inv_bf, W3, b3,
                                           (float*)d_out, B);
}

// Round 7
// 1022.989 us; speedup vs baseline: 1.5626x; 1.5626x over previous
//
#include <hip/hip_runtime.h>
#include <hip/hip_bf16.h>
#include <math.h>

#define IN_DIM 172
#define HID 128
#define TDIM 100
#define KPAD 192

typedef __attribute__((ext_vector_type(8))) short bf16x8;
typedef __attribute__((ext_vector_type(4))) float f32x4;

static __device__ __forceinline__ ushort f2b(float x) {
  unsigned u = __float_as_uint(x);
  u += 0x7FFFu + ((u >> 16) & 1u);
  return (ushort)(u >> 16);
}
static __device__ __forceinline__ float blo(unsigned w) { return __uint_as_float(w << 16); }
static __device__ __forceinline__ float bhi(unsigned w) { return __uint_as_float(w & 0xffff0000u); }

// ---- one-shot weight prep: wpt | wallT(2 layers)+ball | wet(2) | w1t ----
__global__ void k_prep(const float* __restrict__ Wp,
                       const float* __restrict__ Wq, const float* __restrict__ Wk,
                       const float* __restrict__ Wv, const float* __restrict__ Ws,
                       const float* __restrict__ bq, const float* __restrict__ bk,
                       const float* __restrict__ bv, const float* __restrict__ bs,
                       const float* __restrict__ We, const float* __restrict__ W1,
                       ushort* __restrict__ wpt,
                       ushort* __restrict__ wallT0, ushort* __restrict__ wallT1,
                       float* __restrict__ ball0, float* __restrict__ ball1,
                       ushort* __restrict__ wet0, ushort* __restrict__ wet1,
                       ushort* __restrict__ w1t) {
  int i = blockIdx.x * 256 + threadIdx.x;
  if (i < 128 * KPAD) {
    int c = i / KPAD, k = i - c * KPAD;
    wpt[i] = (k < IN_DIM) ? f2b(Wp[k * HID + c]) : (ushort)0;
    return;
  }
  i -= 128 * KPAD;
  if (i < 2 * 512 * 128) {
    int layer = i >> 16;
    int j = i & 65535;
    int col = j >> 7, k = j & 127;
    int m = col >> 7, c = col & 127;
    const float* W = (m == 0) ? Wq : (m == 1) ? Wk : (m == 2) ? Wv : Ws;
    W += (size_t)layer * HID * HID;
    (layer ? wallT1 : wallT0)[j] = f2b(W[k * HID + c]);
    if (k == 0) {
      const float* bb = (m == 0) ? bq : (m == 1) ? bk : (m == 2) ? bv : bs;
      (layer ? ball1 : ball0)[col] = bb[layer * HID + c];
    }
    return;
  }
  i -= 2 * 512 * 128;
  if (i < 2 * 128 * 128) {
    int layer = i >> 14;
    int j = i & 16383;
    int c = j >> 7, t = j & 127;
    (layer ? wet1 : wet0)[j] =
        (t < TDIM) ? f2b(We[((size_t)layer * TDIM + t) * HID + c]) : (ushort)0;
    return;
  }
  i -= 2 * 128 * 128;
  if (i < 128 * 128) {
    int c = i >> 7, k = i & 127;
    w1t[i] = f2b(W1[k * HID + c]);
  }
}

// h = relu(x_all[ids] @ Wp + bp) -> bf16, via MFMA, 64 rows/block
__global__ __launch_bounds__(256) void k_in_mfma(
    const float* __restrict__ x_all, const int* __restrict__ ids,
    const ushort* __restrict__ wpt, const float* __restrict__ bp,
    ushort* __restrict__ h, int n) {
  __shared__ __align__(16) ushort xs[64][200];
  int tid = threadIdx.x;
  long r0 = (long)blockIdx.x * 64;
  for (int i = tid; i < 64 * 28; i += 256) {
    int r = i / 28, c = IN_DIM + (i - r * 28);
    xs[r][c] = 0;
  }
  for (int i = tid; i < 64 * 43; i += 256) {
    int r = i / 43, seg = i - r * 43;
    long row = r0 + r;
    float4 v = make_float4(0.f, 0.f, 0.f, 0.f);
    if (row < n) v = *(const float4*)(x_all + (size_t)ids[row] * IN_DIM + seg * 4);
    ushort4 u;
    u.x = f2b(v.x); u.y = f2b(v.y); u.z = f2b(v.z); u.w = f2b(v.w);
    *(ushort4*)&xs[r][seg * 4] = u;
  }
  __syncthreads();
  int wv = tid >> 6, l = tid & 63;
  int arow = wv * 16 + (l & 15);
  int kb0 = (l >> 4) * 8;
  bf16x8 a[6];
  #pragma unroll
  for (int kk = 0; kk < 6; ++kk) a[kk] = *(const bf16x8*)&xs[arow][kk * 32 + kb0];
  #pragma unroll
  for (int nt = 0; nt < 8; ++nt) {
    int col = nt * 16 + (l & 15);
    const ushort* wcol = wpt + (size_t)col * KPAD + kb0;
    f32x4 acc = {0.f, 0.f, 0.f, 0.f};
    #pragma unroll
    for (int kk = 0; kk < 6; ++kk) {
      bf16x8 bfr = *(const bf16x8*)(wcol + kk * 32);
      acc = __builtin_amdgcn_mfma_f32_16x16x32_bf16(a[kk], bfr, acc, 0, 0, 0);
    }
    float bias = bp[col];
    #pragma unroll
    for (int j = 0; j < 4; ++j) {
      long row = r0 + wv * 16 + (l >> 4) * 4 + j;
      if (row < n) {
        float y = acc[j] + bias;
        h[row * HID + col] = f2b(y > 0.f ? y : 0.f);
      }
    }
  }
}

// fused q/k/v/skip, optionally applying bn(relu(.)) to f32 input on load
template <bool BN_IN>
__global__ __launch_bounds__(512) void k_qkvs(
    const ushort* __restrict__ hbf, const float* __restrict__ xf,
    const float* __restrict__ sums, const float* __restrict__ bng,
    const float* __restrict__ bnb, float inv_n,
    const ushort* __restrict__ wallT, const float* __restrict__ ball,
    ushort* __restrict__ qb, ushort* __restrict__ kbuf, ushort* __restrict__ vb,
    float* __restrict__ ob, int n) {
  __shared__ __align__(16) ushort hs[128][136];
  __shared__ __align__(16) ushort ws[64][136];
  __shared__ float As[128], Bs[128];
  int tid = threadIdx.x;
  if (BN_IN) {
    if (tid < 128) {
      float mean = sums[tid] * inv_n;
      float var = sums[128 + tid] * inv_n - mean * mean;
      float A = bng[tid] * rsqrtf(var + 1e-5f);
      As[tid] = A;
      Bs[tid] = bnb[tid] - mean * A;
    }
    __syncthreads();
  }
  long r0 = (long)blockIdx.x * 128;
  for (int i = tid; i < 128 * 16; i += 512) {
    int r = i >> 4, cseg = i & 15;
    long row = r0 + r;
    int c0 = cseg * 8;
    if (BN_IN) {
      ushort4 ua = {0, 0, 0, 0}, ub = {0, 0, 0, 0};
      if (row < n) {
        const float* xr = xf + row * HID + c0;
        float4 xa = *(const float4*)xr;
        float4 xb = *(const float4*)(xr + 4);
        ua.x = f2b(As[c0 + 0] * fmaxf(xa.x, 0.f) + Bs[c0 + 0]);
        ua.y = f2b(As[c0 + 1] * fmaxf(xa.y, 0.f) + Bs[c0 + 1]);
        ua.z = f2b(As[c0 + 2] * fmaxf(xa.z, 0.f) + Bs[c0 + 2]);
        ua.w = f2b(As[c0 + 3] * fmaxf(xa.w, 0.f) + Bs[c0 + 3]);
        ub.x = f2b(As[c0 + 4] * fmaxf(xb.x, 0.f) + Bs[c0 + 4]);
        ub.y = f2b(As[c0 + 5] * fmaxf(xb.y, 0.f) + Bs[c0 + 5]);
        ub.z = f2b(As[c0 + 6] * fmaxf(xb.z, 0.f) + Bs[c0 + 6]);
        ub.w = f2b(As[c0 + 7] * fmaxf(xb.w, 0.f) + Bs[c0 + 7]);
      }
      *(ushort4*)&hs[r][c0] = ua;
      *(ushort4*)&hs[r][c0 + 4] = ub;
    } else {
      bf16x8 zv = {0, 0, 0, 0, 0, 0, 0, 0};
      bf16x8 v = (row < n) ? *(const bf16x8*)&hbf[row * HID + c0] : zv;
      *(bf16x8*)&hs[r][c0] = v;
    }
  }
  __syncthreads();
  int wv = tid >> 6, l = tid & 63;
  int arow = wv * 16 + (l & 15);
  int kb0 = (l >> 4) * 8;
  bf16x8 a[4];
  #pragma unroll
  for (int kk = 0; kk < 4; ++kk) a[kk] = *(const bf16x8*)&hs[arow][kk * 32 + kb0];

  for (int g = 0; g < 8; ++g) {
    __syncthreads();
    for (int i = tid; i < 64 * 16; i += 512) {
      int c = i >> 4, cseg = i & 15;
      *(bf16x8*)&ws[c][cseg * 8] =
          *(const bf16x8*)&wallT[(size_t)(g * 64 + c) * 128 + cseg * 8];
    }
    __syncthreads();
    #pragma unroll
    for (int nt = 0; nt < 4; ++nt) {
      int colc = nt * 16 + (l & 15);
      int gcol = g * 64 + colc;
      f32x4 acc = {0.f, 0.f, 0.f, 0.f};
      #pragma unroll
      for (int kk = 0; kk < 4; ++kk) {
        bf16x8 bfr = *(const bf16x8*)&ws[colc][kk * 32 + kb0];
        acc = __builtin_amdgcn_mfma_f32_16x16x32_bf16(a[kk], bfr, acc, 0, 0, 0);
      }
      float bias = ball[gcol];
      int m = gcol >> 7, c = gcol & 127;
      #pragma unroll
      for (int j = 0; j < 4; ++j) {
        long row = r0 + wv * 16 + (l >> 4) * 4 + j;
        if (row < n) {
          float y = acc[j] + bias;
          if (m == 3) ob[row * HID + c] = y;
          else {
            ushort* db = (m == 0) ? qb : (m == 1) ? kbuf : vb;
            db[row * HID + c] = f2b(y);
          }
        }
      }
    }
  }
}

// head GEMM: y = bn_relu(ob1 rows) @ W1T + b1 -> f32 z1, 64 rows/block
__global__ __launch_bounds__(256) void k_mfma128_bn(
    const float* __restrict__ xf, const float* __restrict__ sums,
    const float* __restrict__ bng, const float* __restrict__ bnb, float inv_n,
    const ushort* __restrict__ WT, const float* __restrict__ bias,
    float* __restrict__ Y, int n) {
  __shared__ __align__(16) ushort hs[64][136];
  __shared__ float As[128], Bs[128];
  int tid = threadIdx.x;
  if (tid < 128) {
    float mean = sums[tid] * inv_n;
    float var = sums[128 + tid] * inv_n - mean * mean;
    float A = bng[tid] * rsqrtf(var + 1e-5f);
    As[tid] = A;
    Bs[tid] = bnb[tid] - mean * A;
  }
  __syncthreads();
  long r0 = (long)blockIdx.x * 64;
  for (int i = tid; i < 64 * 16; i += 256) {
    int r = i >> 4, cseg = i & 15;
    long row = r0 + r;
    int c0 = cseg * 8;
    ushort4 ua = {0, 0, 0, 0}, ub = {0, 0, 0, 0};
    if (row < n) {
      const float* xr = xf + row * HID + c0;
      float4 xa = *(const float4*)xr;
      float4 xb = *(const float4*)(xr + 4);
      ua.x = f2b(As[c0 + 0] * fmaxf(xa.x, 0.f) + Bs[c0 + 0]);
      ua.y = f2b(As[c0 + 1] * fmaxf(xa.y, 0.f) + Bs[c0 + 1]);
      ua.z = f2b(As[c0 + 2] * fmaxf(xa.z, 0.f) + Bs[c0 + 2]);
      ua.w = f2b(As[c0 + 3] * fmaxf(xa.w, 0.f) + Bs[c0 + 3]);
      ub.x = f2b(As[c0 + 4] * fmaxf(xb.x, 0.f) + Bs[c0 + 4]);
      ub.y = f2b(As[c0 + 5] * fmaxf(xb.y, 0.f) + Bs[c0 + 5]);
      ub.z = f2b(As[c0 + 6] * fmaxf(xb.z, 0.f) + Bs[c0 + 6]);
      ub.w = f2b(As[c0 + 7] * fmaxf(xb.w, 0.f) + Bs[c0 + 7]);
    }
    *(ushort4*)&hs[r][c0] = ua;
    *(ushort4*)&hs[r][c0 + 4] = ub;
  }
  __syncthreads();
  int wv = tid >> 6, l = tid & 63;
  int arow = wv * 16 + (l & 15);
  int kb0 = (l >> 4) * 8;
  bf16x8 a[4];
  #pragma unroll
  for (int kk = 0; kk < 4; ++kk) a[kk] = *(const bf16x8*)&hs[arow][kk * 32 + kb0];
  #pragma unroll
  for (int nt = 0; nt < 8; ++nt) {
    int col = nt * 16 + (l & 15);
    const ushort* wcol = WT + (size_t)col * 128 + kb0;
    f32x4 acc = {0.f, 0.f, 0.f, 0.f};
    #pragma unroll
    for (int kk = 0; kk < 4; ++kk) {
      bf16x8 bfr = *(const bf16x8*)(wcol + kk * 32);
      acc = __builtin_amdgcn_mfma_f32_16x16x32_bf16(a[kk], bfr, acc, 0, 0, 0);
    }
    float bs = bias[col];
    #pragma unroll
    for (int j = 0; j < 4; ++j) {
      long row = r0 + wv * 16 + (l >> 4) * 4 + j;
      if (row < n) Y[row * HID + col] = acc[j] + bs;
    }
  }
}

// ---- counting sort by dst ----
__global__ void k_hist(const int* __restrict__ dst, int* __restrict__ counts, int nE) {
  int e = blockIdx.x * 256 + threadIdx.x;
  if (e < nE) atomicAdd(&counts[dst[e]], 1);
}

__global__ void k_scan_chunk(const int* __restrict__ counts, int* __restrict__ offs,
                             int* __restrict__ chunkSums, int n) {
  __shared__ int ls[256];
  int t = threadIdx.x;
  int base = blockIdx.x * 1024 + t * 4;
  int v[4];
  #pragma unroll
  for (int j = 0; j < 4; ++j) v[j] = (base + j < n) ? counts[base + j] : 0;
  ls[t] = v[0] + v[1] + v[2] + v[3];
  __syncthreads();
  for (int off = 1; off < 256; off <<= 1) {
    int x = (t >= off) ? ls[t - off] : 0;
    __syncthreads();
    ls[t] += x;
    __syncthreads();
  }
  int run = (t == 0) ? 0 : ls[t - 1];
  if (t == 255) chunkSums[blockIdx.x] = ls[255];
  #pragma unroll
  for (int j = 0; j < 4; ++j) {
    if (base + j < n) offs[base + j] = run;
    run += v[j];
  }
}

__global__ void k_scan_tops(int* __restrict__ chunkSums, int nchunks) {
  __shared__ int ls[256];
  int t = threadIdx.x;
  ls[t] = (t < nchunks) ? chunkSums[t] : 0;
  __syncthreads();
  for (int off = 1; off < 256; off <<= 1) {
    int x = (t >= off) ? ls[t - off] : 0;
    __syncthreads();
    ls[t] += x;
    __syncthreads();
  }
  int excl = (t == 0) ? 0 : ls[t - 1];
  if (t < nchunks) chunkSums[t] = excl;
}

__global__ void k_scan_add(int* __restrict__ offs, const int* __restrict__ chunkSums,
                           int n, int nE) {
  int i = blockIdx.x * 256 + threadIdx.x;
  if (i < n) offs[i] += chunkSums[i >> 10];
  if (i == 0) offs[n] = nE;
}

__global__ void k_scatter(const int* __restrict__ src, const int* __restrict__ dst,
                          const float* __restrict__ dts, const int* __restrict__ offs,
                          int* __restrict__ cursor, uint2* __restrict__ edata, int nE) {
  int e = blockIdx.x * 256 + threadIdx.x;
  if (e >= nE) return;
  int d = dst[e];
  int pos = offs[d] + atomicAdd(&cursor[d], 1);
  edata[pos] = make_uint2((unsigned)src[e], __float_as_uint(dts[e]));
}

// e[E][128] = cos(dt*f+p) @ We via MFMA, bf16 out (sorted order)
__global__ __launch_bounds__(256) void k_te_mfma(
    const uint2* __restrict__ edata, const float* __restrict__ freq,
    const float* __restrict__ phase, const ushort* __restrict__ wet,
    ushort* __restrict__ eb, int nE) {
  __shared__ __align__(16) ushort te[64][136];
  __shared__ float dt_s[64];
  __shared__ float fr_s[128], ph_s[128];
  int tid = threadIdx.x;
  if (tid < 128) {
    fr_s[tid] = (tid < TDIM) ? freq[tid] : 0.f;
    ph_s[tid] = (tid < TDIM) ? phase[tid] : 0.f;
  }
  long e0 = (long)blockIdx.x << 6;
  if (tid < 64) dt_s[tid] = (e0 + tid < nE) ? __uint_as_float(edata[e0 + tid].y) : 0.f;
  __syncthreads();
  for (int i = tid; i < 64 * 128; i += 256) {
    int el = i >> 7, t = i & 127;
    float val = (t < TDIM) ? __cosf(dt_s[el] * fr_s[t] + ph_s[t]) : 0.f;
    te[el][t] = f2b(val);
  }
  __syncthreads();
  int wv = tid >> 6, l = tid & 63;
  int arow = wv * 16 + (l & 15);
  int kb0 = (l >> 4) * 8;
  bf16x8 a[4];
  #pragma unroll
  for (int kk = 0; kk < 4; ++kk) a[kk] = *(const bf16x8*)&te[arow][kk * 32 + kb0];
  #pragma unroll
  for (int nt = 0; nt < 8; ++nt) {
    int col = nt * 16 + (l & 15);
    const ushort* wcol = wet + (size_t)col * 128 + kb0;
    f32x4 acc = {0.f, 0.f, 0.f, 0.f};
    #pragma unroll
    for (int kk = 0; kk < 4; ++kk) {
      bf16x8 bfr = *(const bf16x8*)(wcol + kk * 32);
      acc = __builtin_amdgcn_mfma_f32_16x16x32_bf16(a[kk], bfr, acc, 0, 0, 0);
    }
    #pragma unroll
    for (int j = 0; j < 4; ++j) {
      long row = e0 + wv * 16 + (l >> 4) * 4 + j;
      if (row < nE) eb[row * 128 + col] = f2b(acc[j]);
    }
  }
}

// fused attention: one wave per dst, 4 edges/iter (16-lane subgroups), online softmax
__global__ void k_attn(const int* __restrict__ offs, const uint2* __restrict__ edata,
                       const ushort* __restrict__ eb, const ushort* __restrict__ qb,
                       const ushort* __restrict__ kb, const ushort* __restrict__ vb,
                       float* __restrict__ ob, int n) {
  int d = (blockIdx.x * 256 + threadIdx.x) >> 6;
  if (d >= n) return;
  int lane = threadIdx.x & 63;
  int sub = lane >> 4;
  int cl = lane & 15;
  int c0 = cl * 8;
  int beg = offs[d], end = offs[d + 1];
  if (beg == end) return;
  uint4 qw = *(const uint4*)(qb + (size_t)d * HID + c0);
  float q0 = blo(qw.x), q1 = bhi(qw.x), q2 = blo(qw.y), q3 = bhi(qw.y);
  float q4 = blo(qw.z), q5 = bhi(qw.z), q6 = blo(qw.w), q7 = bhi(qw.w);
  float m = -INFINITY, s = 0.f;
  float a0 = 0.f, a1 = 0.f, a2 = 0.f, a3 = 0.f, a4 = 0.f, a5 = 0.f, a6 = 0.f, a7 = 0.f;
  for (int base = beg; base < end; base += 4) {
    int pos = base + sub;
    bool valid = pos < end;
    int pp = valid ? pos : beg;
    int sv = (int)edata[pp].x;
    uint4 kw = *(const uint4*)(kb + (size_t)sv * HID + c0);
    uint4 vw = *(const uint4*)(vb + (size_t)sv * HID + c0);
    uint4 ew = *(const uint4*)(eb + (size_t)pp * HID + c0);
    float e0 = blo(ew.x), e1 = bhi(ew.x), e2 = blo(ew.y), e3 = bhi(ew.y);
    float e4 = blo(ew.z), e5 = bhi(ew.z), e6 = blo(ew.w), e7 = bhi(ew.w);
    float p = q0 * (blo(kw.x) + e0) + q1 * (bhi(kw.x) + e1) +
              q2 * (blo(kw.y) + e2) + q3 * (bhi(kw.y) + e3) +
              q4 * (blo(kw.z) + e4) + q5 * (bhi(kw.z) + e5) +
              q6 * (blo(kw.w) + e6) + q7 * (bhi(kw.w) + e7);
    p += __shfl_xor(p, 1);
    p += __shfl_xor(p, 2);  // per-head dot (4 lanes = 32 cols)
    float av = valid ? p * 0.17677669529663687f : -INFINITY;
    float nm = fmaxf(m, av);
    float sc = (m > -INFINITY) ? __expf(m - nm) : 0.f;
    float pe = valid ? __expf(av - nm) : 0.f;
    m = nm;
    s = s * sc + pe;
    a0 = a0 * sc + pe * (blo(vw.x) + e0);
    a1 = a1 * sc + pe * (bhi(vw.x) + e1);
    a2 = a2 * sc + pe * (blo(vw.y) + e2);
    a3 = a3 * sc + pe * (bhi(vw.y) + e3);
    a4 = a4 * sc + pe * (blo(vw.z) + e4);
    a5 = a5 * sc + pe * (bhi(vw.z) + e5);
    a6 = a6 * sc + pe * (blo(vw.w) + e6);
    a7 = a7 * sc + pe * (bhi(vw.w) + e7);
  }
  // merge the 4 subgroups
  #pragma unroll
  for (int off = 16; off <= 32; off <<= 1) {
    float mo = __shfl_xor(m, off);
    float so = __shfl_xor(s, off);
    float t0 = __shfl_xor(a0, off), t1 = __shfl_xor(a1, off);
    float t2 = __shfl_xor(a2, off), t3 = __shfl_xor(a3, off);
    float t4 = __shfl_xor(a4, off), t5 = __shfl_xor(a5, off);
    float t6 = __shfl_xor(a6, off), t7 = __shfl_xor(a7, off);
    float nm = fmaxf(m, mo);
    float s1 = (m > -INFINITY) ? __expf(m - nm) : 0.f;
    float s2 = (mo > -INFINITY) ? __expf(mo - nm) : 0.f;
    s = s * s1 + so * s2;
    a0 = a0 * s1 + t0 * s2; a1 = a1 * s1 + t1 * s2;
    a2 = a2 * s1 + t2 * s2; a3 = a3 * s1 + t3 * s2;
    a4 = a4 * s1 + t4 * s2; a5 = a5 * s1 + t5 * s2;
    a6 = a6 * s1 + t6 * s2; a7 = a7 * s1 + t7 * s2;
    m = nm;
  }
  if (sub == 0) {
    float inv = 1.f / (s + 1e-16f);
    float4* o = (float4*)(ob + (size_t)d * HID + c0);
    float4 x0 = o[0], x1 = o[1];
    x0.x += a0 * inv; x0.y += a1 * inv; x0.z += a2 * inv; x0.w += a3 * inv;
    x1.x += a4 * inv; x1.y += a5 * inv; x1.z += a6 * inv; x1.w += a7 * inv;
    o[0] = x0; o[1] = x1;
  }
}

template <bool PRE_RELU>
__global__ void k_bn_reduce(const float* __restrict__ X, int n, int C, int shift,
                            float* __restrict__ sums) {
  int col = threadIdx.x & (C - 1);
  int rloc = threadIdx.x >> shift;
  int rpt = 256 >> shift;
  float s = 0.f, s2 = 0.f;
  for (long r = (long)blockIdx.x * rpt + rloc; r < n; r += (long)gridDim.x * rpt) {
    float v = X[r * C + col];
    if (PRE_RELU) v = v > 0.f ? v : 0.f;
    s += v; s2 += v * v;
  }
  __shared__ float ls[256], ls2[256];
  ls[threadIdx.x] = s; ls2[threadIdx.x] = s2;
  __syncthreads();
  if (rloc == 0) {
    for (int j = 1; j < rpt; ++j) { s += ls[j * C + col]; s2 += ls2[j * C + col]; }
    atomicAdd(&sums[col], s);
    atomicAdd(&sums[C + col], s2);
  }
}

// z2 = relu(bn(z1)) @ W2 + b2 (BN fused on load), 16 rows/block
__global__ __launch_bounds__(256) void k_gemm_64(
    const float* __restrict__ X, const float* __restrict__ sums,
    const float* __restrict__ g, const float* __restrict__ be, float inv_n,
    const float* __restrict__ W, const float* __restrict__ b,
    float* __restrict__ Y, int n) {
  __shared__ float xs[16][HID];
  __shared__ float As[128], Bs[128];
  if (threadIdx.x < 128) {
    int c = threadIdx.x;
    float mean = sums[c] * inv_n;
    float var = sums[128 + c] * inv_n - mean * mean;
    float A = g[c] * rsqrtf(var + 1e-5f);
    As[c] = A;
    Bs[c] = be[c] - mean * A;
  }
  __syncthreads();
  int r0 = blockIdx.x * 16;
  for (int idx = threadIdx.x; idx < 16 * HID; idx += 256) {
    int r = idx >> 7, c = idx & 127;
    int row = r0 + r;
    float v = (row < n) ? X[(size_t)row * HID + c] : 0.f;
    v = As[c] * v + Bs[c];
    xs[r][c] = v > 0.f ? v : 0.f;
  }
  __syncthreads();
  int col = threadIdx.x & 63;
  int rg = threadIdx.x >> 6;
  float acc[4] = {0.f, 0.f, 0.f, 0.f};
  #pragma unroll 4
  for (int kk = 0; kk < HID; ++kk) {
    float w = W[kk * 64 + col];
    #pragma unroll
    for (int j = 0; j < 4; ++j) acc[j] += xs[rg + 4 * j][kk] * w;
  }
  float bias = b[col];
  #pragma unroll
  for (int j = 0; j < 4; ++j) {
    int row = r0 + rg + 4 * j;
    if (row < n) Y[(size_t)row * 64 + col] = acc[j] + bias;
  }
}

// out = relu(bn(z2)) . W3 + b3 (BN fused), one wave per row
__global__ __launch_bounds__(256) void k_final(
    const float* __restrict__ z2, const float* __restrict__ sums,
    const float* __restrict__ g2, const float* __restrict__ be2, float inv_n,
    const float* __restrict__ W3, const float* __restrict__ b3,
    float* __restrict__ out, int n) {
  int wave = threadIdx.x >> 6, lane = threadIdx.x & 63;
  int row = blockIdx.x * 4 + wave;
  if (row >= n) return;
  float z = z2[(size_t)row * 64 + lane];
  float mean = sums[lane] * inv_n;
  float var = sums[64 + lane] * inv_n - mean * mean;
  float v = g2[lane] * (z - mean) * rsqrtf(var + 1e-5f) + be2[lane];
  v = v > 0.f ? v : 0.f;
  float pv = v * W3[lane];
  pv += __shfl_xor(pv, 1);
  pv += __shfl_xor(pv, 2);
  pv += __shfl_xor(pv, 4);
  pv += __shfl_xor(pv, 8);
  pv += __shfl_xor(pv, 16);
  pv += __shfl_xor(pv, 32);
  if (lane == 0) out[row] = pv + b3[0];
}

extern "C" void kernel_launch(void* const* d_in, const int* in_sizes, int n_in,
                              void* d_out, int out_size, void* d_ws, size_t ws_size,
                              hipStream_t stream) {
  const float* x_all = (const float*)d_in[0];
  const int* ids = (const int*)d_in[1];
  const int* esrc = (const int*)d_in[2];
  const int* edst = (const int*)d_in[3];
  const float* dts = (const float*)d_in[4];
  const float* freq = (const float*)d_in[6];
  const float* phase = (const float*)d_in[7];
  const float* Wp = (const float*)d_in[8];
  const float* bp = (const float*)d_in[9];
  const float* Wq = (const float*)d_in[10];
  const float* bq = (const float*)d_in[11];
  const float* Wk = (const float*)d_in[12];
  const float* bk = (const float*)d_in[13];
  const float* Wv = (const float*)d_in[14];
  const float* bv = (const float*)d_in[15];
  const float* We = (const float*)d_in[16];
  const float* Wskip = (const float*)d_in[17];
  const float* bskip = (const float*)d_in[18];
  const float* bn_g = (const float*)d_in[19];
  const float* bn_b = (const float*)d_in[20];
  const float* W1 = (const float*)d_in[21];
  const float* b1 = (const float*)d_in[22];
  const float* g1 = (const float*)d_in[23];
  const float* be1 = (const float*)d_in[24];
  const float* W2 = (const float*)d_in[25];
  const float* b2 = (const float*)d_in[26];
  const float* g2 = (const float*)d_in[27];
  const float* be2 = (const float*)d_in[28];
  const float* W3 = (const float*)d_in[29];
  const float* b3 = (const float*)d_in[30];

  size_t n = (size_t)in_sizes[1];
  size_t nE = (size_t)in_sizes[2] / 2;
  int B = out_size;

  char* pc = (char*)d_ws;
  auto alloc = [&](size_t bytes) { char* r = pc; pc += (bytes + 255) & ~(size_t)255; return r; };
  ushort* h    = (ushort*)alloc(n * HID * 2);
  ushort* qb   = (ushort*)alloc(n * HID * 2);
  ushort* kb   = (ushort*)alloc(n * HID * 2);
  ushort* vb   = (ushort*)alloc(n * HID * 2);
  float*  ob0  = (float*)alloc(n * HID * 4);
  float*  ob1  = (float*)alloc(n * HID * 4);
  ushort* eb   = (ushort*)alloc(nE * HID * 2);
  uint2* edata = (uint2*)alloc(nE * 8);
  int* offs    = (int*)alloc((n + 1) * 4);
  int* chunkS  = (int*)alloc(256 * 4);
  // bulk-zeroed region: counts/cursor x2 layers + 4 sums buffers
  size_t zbytes = 4 * n * 4 + 4 * 256 * 4;
  char* zb = alloc(zbytes);
  int* counts0 = (int*)zb;
  int* cursor0 = counts0 + n;
  int* counts1 = cursor0 + n;
  int* cursor1 = counts1 + n;
  float* sumsL0 = (float*)(cursor1 + n);
  float* sumsL1 = sumsL0 + 256;
  float* sumsZ1 = sumsL1 + 256;
  float* sumsZ2 = sumsZ1 + 256;
  ushort* wpt    = (ushort*)alloc(128 * KPAD * 2);
  ushort* wallT0 = (ushort*)alloc(512 * 128 * 2);
  ushort* wallT1 = (ushort*)alloc(512 * 128 * 2);
  float* ball0   = (float*)alloc(512 * 4);
  float* ball1   = (float*)alloc(512 * 4);
  ushort* wet0   = (ushort*)alloc(128 * 128 * 2);
  ushort* wet1   = (ushort*)alloc(128 * 128 * 2);
  ushort* w1t    = (ushort*)alloc(128 * 128 * 2);
  float* z1      = (float*)alloc((size_t)B * HID * 4);
  float* z2      = (float*)alloc((size_t)B * 64 * 4);

  int gn64 = (int)((n + 63) / 64);
  int gn128 = (int)((n + 127) / 128);
  int ge256 = (int)((nE + 255) / 256);
  int eblk = (int)((nE + 63) / 64);
  int nchunks = (int)((n + 1023) / 1024);
  float inv_nf = 1.f / (float)n;
  float inv_bf = 1.f / (float)B;

  hipMemsetAsync(zb, 0, zbytes, stream);
  k_prep<<<(128 * KPAD + 2 * 512 * 128 + 2 * 128 * 128 + 128 * 128 + 255) / 256, 256, 0, stream>>>(
      Wp, Wq, Wk, Wv, Wskip, bq, bk, bv, bskip, We, W1,
      wpt, wallT0, wallT1, ball0, ball1, wet0, wet1, w1t);
  k_in_mfma<<<gn64, 256, 0, stream>>>(x_all, ids, wpt, bp, h, (int)n);

  for (int i = 0; i < 2; ++i) {
    const int* src_i = esrc + i * nE;
    const int* dst_i = edst + i * nE;
    const float* dts_i = dts + i * nE;
    int* counts = i ? counts1 : counts0;
    int* cursor = i ? cursor1 : cursor0;
    const ushort* wallT = i ? wallT1 : wallT0;
    const float* ball = i ? ball1 : ball0;
    const ushort* wet = i ? wet1 : wet0;
    float* ob = i ? ob1 : ob0;

    if (i == 0)
      k_qkvs<false><<<gn128, 512, 0, stream>>>(h, nullptr, nullptr, nullptr, nullptr, 0.f,
                                               wallT, ball, qb, kb, vb, ob, (int)n);
    else
      k_qkvs<true><<<gn128, 512, 0, stream>>>(nullptr, ob0, sumsL0, bn_g, bn_b, inv_nf,
                                              wallT, ball, qb, kb, vb, ob, (int)n);

    k_hist<<<ge256, 256, 0, stream>>>(dst_i, counts, (int)nE);
    k_scan_chunk<<<nchunks, 256, 0, stream>>>(counts, offs, chunkS, (int)n);
    k_scan_tops<<<1, 256, 0, stream>>>(chunkS, nchunks);
    k_scan_add<<<(int)((n + 255) / 256), 256, 0, stream>>>(offs, chunkS, (int)n, (int)nE);
    k_scatter<<<ge256, 256, 0, stream>>>(src_i, dst_i, dts_i, offs, cursor, edata, (int)nE);
    k_te_mfma<<<eblk, 256, 0, stream>>>(edata, freq, phase, wet, eb, (int)nE);
    k_attn<<<(int)((n + 3) / 4), 256, 0, stream>>>(offs, edata, eb, qb, kb, vb, ob, (int)n);
    k_bn_reduce<true><<<512, 256, 0, stream>>>(ob, (int)n, HID, 7, i ? sumsL1 : sumsL0);
  }

  // MLP head on first B rows (BN of layer-1 fused into the GEMM input)
  k_mfma128_bn<<<(B + 63) / 64, 256, 0, stream>>>(ob1, sumsL1, bn_g + HID, bn_b + HID,
                                                  inv_nf, w1t, b1, z1, B);
  k_bn_reduce<false><<<512, 256, 0, stream>>>(z1, B, HID, 7, sumsZ1);
  k_gemm_64<<<(B + 15) / 16, 256, 0, stream>>>(z1, sumsZ1, g1, be1, inv_bf, W2, b2, z2, B);
  k_bn_reduce<false><<<512, 256, 0, stream>>>(z2, B, 64, 6, sumsZ2);
  k_final<<<(B + 3) / 4, 256, 0, stream>>>(z2, sumsZ2, g2, be2, inv_bf, W3, b3,
                                           (float*)d_out, B);
}